// Round 8
// baseline (123.361 us; speedup 1.0000x reference)
//
#include <hip/hip_runtime.h>

#define T_DIM 1024
#define B_DIM 4
#define D_DIM 512
#define DQ (D_DIM / 4)                 // 128 float4 per row
#define NROWS (T_DIM * B_DIM)
#define SSTR ((size_t)NROWS * 4 * DQ)  // scale-slab stride in float4 units

// ---------------- Kernel 1: per-(b,t) inverse L2 norm over D ----------------
__global__ __launch_bounds__(256) void norm_kernel(const float* __restrict__ x,
                                                   float* __restrict__ inv) {
    const int wave = threadIdx.x >> 6;
    const int lane = threadIdx.x & 63;
    const int row  = blockIdx.x * 4 + wave;          // grid = NROWS/4 exactly
    const float4* xr = reinterpret_cast<const float4*>(x) + (size_t)row * DQ;
    float4 a = xr[lane];
    float4 c = xr[lane + 64];
    float s2 = a.x*a.x + a.y*a.y + a.z*a.z + a.w*a.w
             + c.x*c.x + c.y*c.y + c.z*c.z + c.w*c.w;
    #pragma unroll
    for (int off = 32; off > 0; off >>= 1) s2 += __shfl_xor(s2, off, 64);
    if (lane == 0) inv[row] = 1.0f / fmaxf(sqrtf(s2), 1e-12f);
}

// ---------------- Kernel 2: scale-specialized, W in registers ----------------
// DIAGNOSTIC ROUND: per-block work repeated `reps` times (runtime arg, opaque
// pointers per rep => no DSE / no hoisting). Output is byte-identical to R7;
// purpose is to push this dispatch above the fillBuffer dispatches so rocprof's
// top-5 finally shows OUR counters (FETCH/WRITE/VALUBusy/Occupancy).
__device__ __forceinline__ void fma4(float4& a, float wt, const float4& v) {
    a.x += wt * v.x; a.y += wt * v.y; a.z += wt * v.z; a.w += wt * v.w;
}

template<int S, int JB, int OH>
__device__ __forceinline__ void pool_scale(const float* __restrict__ x,
                                           const float* __restrict__ inv,
                                           const float* __restrict__ W,
                                           float* __restrict__ out,
                                           int si, int b, int j0, int o0,
                                           int reps) {
    const int q = threadIdx.x;                        // 0..127
    float w[OH][S];                                   // uniform, loaded once/block
    #pragma unroll
    for (int oo = 0; oo < OH; ++oo)
        #pragma unroll
        for (int k = 0; k < S; ++k)
            w[oo][k] = W[(o0 + oo) * S + k];

    const float4* xq   = reinterpret_cast<const float4*>(x) + (size_t)b * T_DIM * DQ + q;
    const float*  invb = inv + b * T_DIM;
    float4* outb = reinterpret_cast<float4*>(out) + (size_t)si * SSTR
                 + (size_t)o0 * DQ + q;

    for (int rep = 0; rep < reps; ++rep) {
        const float4* xq_r  = xq;
        const float*  inv_r = invb;
        asm volatile("" : "+v"(xq_r), "+v"(inv_r));   // opaque: redo work each rep
        #pragma unroll 1
        for (int jj = 0; jj < JB; ++jj) {
            const int j  = j0 + jj;
            const int lo = max(0, j - S / 2 + 1);
            const int hi = min(j + S / 2, T_DIM - 1);
            float4 acc[OH];
            #pragma unroll
            for (int oo = 0; oo < OH; ++oo) acc[oo] = make_float4(0.f, 0.f, 0.f, 0.f);
            #pragma unroll
            for (int k = 0; k < S; ++k) {             // tap k -> row lo+k
                const int t = lo + k;
                if (t <= hi) {                        // uniform predicate
                    float4 xv = xq_r[(size_t)t * DQ];
                    const float s = inv_r[t];
                    xv.x *= s; xv.y *= s; xv.z *= s; xv.w *= s;
                    #pragma unroll
                    for (int oo = 0; oo < OH; ++oo)
                        fma4(acc[oo], w[oo][k], xv);
                }
            }
            const int n = j * B_DIM + b;              // reference row order (T, B)
            float4* op = outb + (size_t)n * 4 * DQ;
            #pragma unroll
            for (int oo = 0; oo < OH; ++oo)
                op[(size_t)oo * DQ] = acc[oo];
        }
    }
}

// Grid = 2944 blocks: [0,128) s4 | [128,384) s8 | [384,896) s16 | [896,2944) s32.
__global__ __launch_bounds__(128, 4) void pool_kernel(const float* __restrict__ x,
                                                      const float* __restrict__ inv,
                                                      const float* __restrict__ W0,
                                                      const float* __restrict__ W1,
                                                      const float* __restrict__ W2,
                                                      const float* __restrict__ W3,
                                                      float* __restrict__ out,
                                                      int reps) {
    const int bid = blockIdx.x;
    if (bid < 128) {                                  // scale 4: JB=32, 4 o
        const int g = (bid & 7) * 16 + (bid >> 3);
        pool_scale<4, 32, 4>(x, inv, W0, out, 0, g >> 5, (g & 31) * 32, 0, reps);
    } else if (bid < 384) {                           // scale 8: JB=16, 4 o
        const int l = bid - 128;
        const int g = (l & 7) * 32 + (l >> 3);
        pool_scale<8, 16, 4>(x, inv, W1, out, 1, g >> 6, (g & 63) * 16, 0, reps);
    } else if (bid < 896) {                           // scale 16: JB=8, 4 o
        const int l = bid - 384;
        const int g = (l & 7) * 64 + (l >> 3);
        pool_scale<16, 8, 4>(x, inv, W2, out, 2, g >> 7, (g & 127) * 8, 0, reps);
    } else {                                          // scale 32: JB=4, 2 o per block
        const int l = bid - 896;
        const int g = (l & 7) * 256 + (l >> 3);
        const int b = g >> 9;
        const int r = g & 511;
        pool_scale<32, 4, 2>(x, inv, W3, out, 3, b, (r >> 1) * 4, (r & 1) * 2, reps);
    }
}

extern "C" void kernel_launch(void* const* d_in, const int* in_sizes, int n_in,
                              void* d_out, int out_size, void* d_ws, size_t ws_size,
                              hipStream_t stream) {
    const float* x  = (const float*)d_in[0];
    const float* W0 = (const float*)d_in[1];
    const float* W1 = (const float*)d_in[2];
    const float* W2 = (const float*)d_in[3];
    const float* W3 = (const float*)d_in[4];
    float* out = (float*)d_out;
    float* inv = (float*)d_ws;   // NROWS floats = 16 KB scratch

    norm_kernel<<<NROWS / 4, 256, 0, stream>>>(x, inv);
    pool_kernel<<<2944, 128, 0, stream>>>(x, inv, W0, W1, W2, W3, out, 3);
}

// Round 9
// 96.735 us; speedup vs baseline: 1.2752x; 1.2752x over previous
//
#include <hip/hip_runtime.h>

#define T_DIM 1024
#define B_DIM 4
#define D_DIM 512
#define DQ (D_DIM / 4)                 // 128 float4 per row
#define NROWS (T_DIM * B_DIM)
#define SSTR ((size_t)NROWS * 4 * DQ)  // scale-slab stride in float4 units
#define RPOS 128                       // j-positions per sweep band
#define NSTEP (T_DIM / RPOS)           // 8 sweep steps

// ---------------- Kernel 1: per-(b,t) inverse L2 norm over D ----------------
__global__ __launch_bounds__(256) void norm_kernel(const float* __restrict__ x,
                                                   float* __restrict__ inv) {
    const int wave = threadIdx.x >> 6;
    const int lane = threadIdx.x & 63;
    const int row  = blockIdx.x * 4 + wave;          // grid = NROWS/4 exactly
    const float4* xr = reinterpret_cast<const float4*>(x) + (size_t)row * DQ;
    float4 a = xr[lane];
    float4 c = xr[lane + 64];
    float s2 = a.x*a.x + a.y*a.y + a.z*a.z + a.w*a.w
             + c.x*c.x + c.y*c.y + c.z*c.z + c.w*c.w;
    #pragma unroll
    for (int off = 32; off > 0; off >>= 1) s2 += __shfl_xor(s2, off, 64);
    if (lane == 0) inv[row] = 1.0f / fmaxf(sqrtf(s2), 1e-12f);
}

// ---------------- Kernel 2: lockstep j-sweep, W in SGPRs --------------------
// Block = (scale si, batch b, o-group, j-offset r). Steps m=0..NSTEP-1 process
// j = m*RPOS + r IN ORDER, so all resident blocks of a scale write one dense
// j-band of the output slab at a time (DRAM page locality for the store path).
__device__ __forceinline__ void fma4(float4& a, float wt, const float4& v) {
    a.x += wt * v.x; a.y += wt * v.y; a.z += wt * v.z; a.w += wt * v.w;
}

template<int S, int OH>
__device__ __forceinline__ void sweep_scale(const float* __restrict__ x,
                                            const float* __restrict__ inv,
                                            const float* __restrict__ W,
                                            float* __restrict__ out,
                                            int si, int b, int o0, int r) {
    const int q = threadIdx.x;                        // 0..127
    float w[OH][S];                                   // uniform -> SGPRs
    #pragma unroll
    for (int oo = 0; oo < OH; ++oo)
        #pragma unroll
        for (int k = 0; k < S; ++k)
            w[oo][k] = W[(o0 + oo) * S + k];

    const float4* xq   = reinterpret_cast<const float4*>(x) + (size_t)b * T_DIM * DQ + q;
    const float*  invb = inv + b * T_DIM;
    float4* outb = reinterpret_cast<float4*>(out) + (size_t)si * SSTR
                 + (size_t)o0 * DQ + q;

    #pragma unroll 1
    for (int m = 0; m < NSTEP; ++m) {                 // ordered sweep over j-bands
        const int j  = m * RPOS + r;
        const int lo = max(0, j - S / 2 + 1);
        const int hi = min(j + S / 2, T_DIM - 1);
        float4 acc[OH];
        #pragma unroll
        for (int oo = 0; oo < OH; ++oo) acc[oo] = make_float4(0.f, 0.f, 0.f, 0.f);
        #pragma unroll
        for (int k = 0; k < S; ++k) {                 // tap k -> row lo+k
            const int t = lo + k;
            if (t <= hi) {                            // uniform predicate
                float4 xv = xq[(size_t)t * DQ];
                const float s = invb[t];
                xv.x *= s; xv.y *= s; xv.z *= s; xv.w *= s;
                #pragma unroll
                for (int oo = 0; oo < OH; ++oo)
                    fma4(acc[oo], w[oo][k], xv);
            }
        }
        const int n = j * B_DIM + b;                  // reference row order (T, B)
        float4* op = outb + (size_t)n * 4 * DQ;
        #pragma unroll
        for (int oo = 0; oo < OH; ++oo)
            op[(size_t)oo * DQ] = acc[oo];
    }
}

// Grid = 20 combos * RPOS blocks.
// combo: 0-3 = s4 (b=combo) | 4-7 = s8 | 8-11 = s16 | 12-19 = s32 (b, o-half).
__global__ __launch_bounds__(128, 4) void pool_kernel(const float* __restrict__ x,
                                                      const float* __restrict__ inv,
                                                      const float* __restrict__ W0,
                                                      const float* __restrict__ W1,
                                                      const float* __restrict__ W2,
                                                      const float* __restrict__ W3,
                                                      float* __restrict__ out) {
    const int r     = blockIdx.x & (RPOS - 1);
    const int combo = blockIdx.x >> 7;                // RPOS == 128
    if (combo < 4) {
        sweep_scale<4, 4>(x, inv, W0, out, 0, combo, 0, r);
    } else if (combo < 8) {
        sweep_scale<8, 4>(x, inv, W1, out, 1, combo - 4, 0, r);
    } else if (combo < 12) {
        sweep_scale<16, 4>(x, inv, W2, out, 2, combo - 8, 0, r);
    } else {
        const int c = combo - 12;                     // 0..7
        sweep_scale<32, 2>(x, inv, W3, out, 3, c >> 1, (c & 1) * 2, r);
    }
}

extern "C" void kernel_launch(void* const* d_in, const int* in_sizes, int n_in,
                              void* d_out, int out_size, void* d_ws, size_t ws_size,
                              hipStream_t stream) {
    const float* x  = (const float*)d_in[0];
    const float* W0 = (const float*)d_in[1];
    const float* W1 = (const float*)d_in[2];
    const float* W2 = (const float*)d_in[3];
    const float* W3 = (const float*)d_in[4];
    float* out = (float*)d_out;
    float* inv = (float*)d_ws;   // NROWS floats = 16 KB scratch

    norm_kernel<<<NROWS / 4, 256, 0, stream>>>(x, inv);
    pool_kernel<<<20 * RPOS, 128, 0, stream>>>(x, inv, W0, W1, W2, W3, out);
}

// Round 11
// 41.338 us; speedup vs baseline: 2.9842x; 2.3401x over previous
//
#include <hip/hip_runtime.h>

#define T_DIM 1024
#define B_DIM 4
#define D_DIM 512
#define DQ (D_DIM / 4)                 // 128 float4 per row
#define NROWS (T_DIM * B_DIM)
#define SSTR ((size_t)NROWS * 4 * DQ)  // scale-slab stride in float4 units

// ---------------- Kernel 1: per-(b,t) inverse L2 norm over D ----------------
__global__ __launch_bounds__(256) void norm_kernel(const float* __restrict__ x,
                                                   float* __restrict__ inv) {
    const int wave = threadIdx.x >> 6;
    const int lane = threadIdx.x & 63;
    const int row  = blockIdx.x * 4 + wave;          // grid = NROWS/4 exactly
    const float4* xr = reinterpret_cast<const float4*>(x) + (size_t)row * DQ;
    float4 a = xr[lane];
    float4 c = xr[lane + 64];
    float s2 = a.x*a.x + a.y*a.y + a.z*a.z + a.w*a.w
             + c.x*c.x + c.y*c.y + c.z*c.z + c.w*c.w;
    #pragma unroll
    for (int off = 32; off > 0; off >>= 1) s2 += __shfl_xor(s2, off, 64);
    if (lane == 0) inv[row] = 1.0f / fmaxf(sqrtf(s2), 1e-12f);
}

// ---------------- Kernel 2: one output row n per block, TERMINAL stores -----
// Key property: within a wave, NO load is ever issued after a store, so the
// shared vmcnt counter never makes compute wait on store retirement. All 4
// scales computed from one streamed 32-row window; 16-store burst at the end.
__device__ __forceinline__ void fma4(float4& a, float wt, const float4& v) {
    a.x += wt * v.x; a.y += wt * v.y; a.z += wt * v.z; a.w += wt * v.w;
}

template<int S>
__device__ __forceinline__ void gen_scale(const float* __restrict__ W,
                                          const float4* __restrict__ xq,
                                          const float* __restrict__ inv,
                                          int j, int b,
                                          float4* acc) {   // acc[0..3]
    const int lo = max(0, j - S / 2 + 1);
    const int hi = min(j + S / 2, T_DIM - 1);
    for (int t = lo; t <= hi; ++t) {
        float4 xv = xq[(size_t)t * DQ];
        const float s = inv[b * T_DIM + t];
        xv.x *= s; xv.y *= s; xv.z *= s; xv.w *= s;
        const int kk = t - lo;
        fma4(acc[0], W[0 * S + kk], xv);
        fma4(acc[1], W[1 * S + kk], xv);
        fma4(acc[2], W[2 * S + kk], xv);
        fma4(acc[3], W[3 * S + kk], xv);
    }
}

__global__ __launch_bounds__(128) void pool_kernel(const float* __restrict__ x,
                                                   const float* __restrict__ inv,
                                                   const float* __restrict__ W0,
                                                   const float* __restrict__ W1,
                                                   const float* __restrict__ W2,
                                                   const float* __restrict__ W3,
                                                   float* __restrict__ out) {
    // XCD-chunked bijective map: XCD k handles 512 consecutive n.
    const int n = (blockIdx.x & 7) * (NROWS / 8) + (blockIdx.x >> 3);
    const int j = n >> 2;                            // n = j*B + b (ref order)
    const int b = n & 3;
    const int q = threadIdx.x;                       // one float4-quad per thread
    const float4* xq   = reinterpret_cast<const float4*>(x) + (size_t)b * T_DIM * DQ + q;
    const float*  invb = inv + b * T_DIM;

    float4 acc[16];                                  // [si*4 + o], compile-time idx
    #pragma unroll
    for (int i = 0; i < 16; ++i) acc[i] = make_float4(0.f, 0.f, 0.f, 0.f);

    if (j >= 15 && j <= T_DIM - 17) {
        // Interior: stream the 32-row window once, feed all 4 scales.
        const int t0 = j - 15;
        #pragma unroll
        for (int k = 0; k < 32; ++k) {
            float4 xv = xq[(size_t)(t0 + k) * DQ];
            const float s = invb[t0 + k];            // uniform -> s_load
            xv.x *= s; xv.y *= s; xv.z *= s; xv.w *= s;
            if (k >= 14 && k < 18) {                 // scale 4, base 14
                #pragma unroll
                for (int o = 0; o < 4; ++o) fma4(acc[0 + o], W0[o * 4 + (k - 14)], xv);
            }
            if (k >= 12 && k < 20) {                 // scale 8, base 12
                #pragma unroll
                for (int o = 0; o < 4; ++o) fma4(acc[4 + o], W1[o * 8 + (k - 12)], xv);
            }
            if (k >= 8 && k < 24) {                  // scale 16, base 8
                #pragma unroll
                for (int o = 0; o < 4; ++o) fma4(acc[8 + o], W2[o * 16 + (k - 8)], xv);
            }
            {                                        // scale 32, base 0
                #pragma unroll
                for (int o = 0; o < 4; ++o) fma4(acc[12 + o], W3[o * 32 + k], xv);
            }
        }
    } else {
        // Edge rows (124 of 4096 blocks): verified masked/shifted path.
        gen_scale<4 >(W0, xq, inv, j, b, &acc[0]);
        gen_scale<8 >(W1, xq, inv, j, b, &acc[4]);
        gen_scale<16>(W2, xq, inv, j, b, &acc[8]);
        gen_scale<32>(W3, xq, inv, j, b, &acc[12]);
    }

    // Terminal store burst: nothing in this wave waits on these.
    float4* outq = reinterpret_cast<float4*>(out) + (size_t)n * 4 * DQ + q;
    #pragma unroll
    for (int si = 0; si < 4; ++si)
        #pragma unroll
        for (int o = 0; o < 4; ++o)
            outq[(size_t)si * SSTR + (size_t)o * DQ] = acc[si * 4 + o];
}

extern "C" void kernel_launch(void* const* d_in, const int* in_sizes, int n_in,
                              void* d_out, int out_size, void* d_ws, size_t ws_size,
                              hipStream_t stream) {
    const float* x  = (const float*)d_in[0];
    const float* W0 = (const float*)d_in[1];
    const float* W1 = (const float*)d_in[2];
    const float* W2 = (const float*)d_in[3];
    const float* W3 = (const float*)d_in[4];
    float* out = (float*)d_out;
    float* inv = (float*)d_ws;   // NROWS floats = 16 KB scratch

    norm_kernel<<<NROWS / 4, 256, 0, stream>>>(x, inv);
    pool_kernel<<<NROWS, 128, 0, stream>>>(x, inv, W0, W1, W2, W3, out);
}